// Round 1
// baseline (5372.908 us; speedup 1.0000x reference)
//
#include <hip/hip_runtime.h>
#include <math.h>

typedef float v4 __attribute__((ext_vector_type(4)));
typedef unsigned long long u64;

static constexpr int B_ = 32;
static constexpr int S_ = 2048;
static constexpr int E_ = 512;
static constexpr int V_ = 32000;
static constexpr float EPS_ = 1e-6f;
static constexpr int NH_ = 8;     // blocks (column slices) per batch
static constexpr int CH_ = 64;    // columns per block

// ---------------------------------------------------------------------------
// K1: 8-blocks-per-batch scan, 256 blocks x 1024 threads (1 block/CU).
// NEW structure vs previous version:
//  * wave w owns 4 columns (c0+4w..+3); lane l owns rows 8l..8l+7.
//    Column sums finish with a 6-stage butterfly INSIDE one wave ->
//    no part[] LDS stage, no serial wave0 col-reduce, publish ~300cy earlier.
//  * per-block LN partial stats (S,Q) are published as 2 extra tagged words;
//    consumers sum 8 scalars instead of a 512-wide post-poll reduce.
//  * role split: wave0 handles stats (reduce+publish+poll), waves 8..15 poll
//    the 512 values into LDS -> stats RT and values RT overlap, B2 waits on
//    max() not sum. Barriers per step: 3 (was 4).
// Exchange protocol (tagged u64, parity double-buffer, relaxed agent atomics)
// is unchanged from the proven version.
// ---------------------------------------------------------------------------
__global__ __launch_bounds__(1024) void scan8w(
    const int* __restrict__ seq,     // (B,S)
    const float* __restrict__ emb,   // (V,E)
    const float* __restrict__ Wdec,  // (E,E) row-major
    const float* __restrict__ bdec,  // (E)
    const float* __restrict__ gamma, // (E)
    const float* __restrict__ beta,  // (E)
    float* __restrict__ zout,        // (B,E)
    u64* __restrict__ zpub)          // values (B,2,E) + stats (B,2,2,8)
{
    __shared__ __align__(16) float zs[E_];     // z_in
    __shared__ __align__(16) float zmbuf[E_];  // polled zmid values
    __shared__ float sred[16][2];              // per-wave (s,q)
    __shared__ float munv[2];                  // mu, inv
    __shared__ int   seq_l[S_];

    const int bid  = blockIdx.x;
    const int b    = bid & 31;    // batch
    const int h    = bid >> 5;    // slice 0..7
    const int c0   = h * CH_;
    const int tid  = threadIdx.x;
    const int wv   = tid >> 6;    // 16 waves
    const int lane = tid & 63;

    // --- W slice into VGPRs: wave wv -> cols c0+4wv..+3, lane -> rows 8l..+7
    v4 w[8];
    {
        const float* wp = Wdec + (size_t)(8 * lane) * E_ + c0 + 4 * wv;
        #pragma unroll
        for (int q = 0; q < 8; ++q) {
            const float* p = wp + (size_t)q * E_;
            asm volatile("global_load_dwordx4 %0, %1, off\n\ts_waitcnt vmcnt(0)"
                         : "=v"(w[q]) : "v"(p));
        }
    }

    const int* seqb = seq + (size_t)b * S_;
    for (int i = tid; i < S_; i += 1024) seq_l[i] = seqb[i];

    const float gmm = (tid < E_) ? gamma[tid] : 0.f;
    const float btt = (tid < E_) ? beta[tid] : 0.f;
    const v4 bd4 = *(const v4*)(bdec + c0 + 4 * wv);
    const float sqrtE = sqrtf(512.0f);
    u64* zpb = zpub + (size_t)b * 2 * E_;                       // values
    u64* zst = zpub + (size_t)B_ * 2 * E_ + (size_t)b * 32;     // [p][sq][8]

    __syncthreads();
    if (tid < E_) zs[tid] = emb[(size_t)seq_l[0] * E_ + tid] * sqrtE;  // x_0
    __syncthreads();

    for (int t = 0; t < S_; ++t) {
        const int p = t & 1;
        const unsigned tag = (unsigned)(t + 1);

        // prefetch next embedding row (consumed at step end)
        const int tn = seq_l[(t + 1 < S_) ? t + 1 : t];
        float e = 0.f;
        if (tid < E_) e = emb[(size_t)tn * E_ + tid];

        // --- matvec: lane's 8 rows x wave's 4 cols ---
        const v4 za = *(const v4*)&zs[8 * lane];
        const v4 zb = *(const v4*)&zs[8 * lane + 4];
        v4 acc = za.x * w[0];
        acc += za.y * w[1];
        acc += za.z * w[2];
        acc += za.w * w[3];
        acc += zb.x * w[4];
        acc += zb.y * w[5];
        acc += zb.z * w[6];
        acc += zb.w * w[7];
        // butterfly allreduce over the 64 lanes -> full column sums
        #pragma unroll
        for (int m = 1; m < 64; m <<= 1) {
            acc.x += __shfl_xor(acc.x, m);
            acc.y += __shfl_xor(acc.y, m);
            acc.z += __shfl_xor(acc.z, m);
            acc.w += __shfl_xor(acc.w, m);
        }
        const v4 zp4 = *(const v4*)&zs[c0 + 4 * wv];   // uniform: broadcast
        const v4 zm4 = acc + zp4 + bd4;                // zmid for 4 cols

        // --- publish values immediately (lanes 0..3, one element each) ---
        if (lane < 4) {
            const float zv = (lane == 0) ? zm4.x : (lane == 1) ? zm4.y
                           : (lane == 2) ? zm4.z : zm4.w;
            union { float f; unsigned u; } cv; cv.f = zv;
            __hip_atomic_store(&zpb[p * E_ + c0 + 4 * wv + lane],
                               ((u64)tag << 32) | cv.u,
                               __ATOMIC_RELAXED, __HIP_MEMORY_SCOPE_AGENT);
        }
        // --- per-wave LN partial stats ---
        if (lane == 0) {
            sred[wv][0] = zm4.x + zm4.y + zm4.z + zm4.w;
            sred[wv][1] = zm4.x * zm4.x + zm4.y * zm4.y
                        + zm4.z * zm4.z + zm4.w * zm4.w;
        }
        __syncthreads();                                   // B1

        if (wv == 0) {
            // block stats: reduce 16 wave-partials, publish, poll 8 blocks
            float s = 0.f, q = 0.f;
            if (lane < 16) { s = sred[lane][0]; q = sred[lane][1]; }
            s += __shfl_down(s, 8);  q += __shfl_down(q, 8);
            s += __shfl_down(s, 4);  q += __shfl_down(q, 4);
            s += __shfl_down(s, 2);  q += __shfl_down(q, 2);
            s += __shfl_down(s, 1);  q += __shfl_down(q, 1);
            if (lane == 0) {
                union { float f; unsigned u; } c1, c2; c1.f = s; c2.f = q;
                __hip_atomic_store(&zst[p * 16 + 0 + h], ((u64)tag << 32) | c1.u,
                                   __ATOMIC_RELAXED, __HIP_MEMORY_SCOPE_AGENT);
                __hip_atomic_store(&zst[p * 16 + 8 + h], ((u64)tag << 32) | c2.u,
                                   __ATOMIC_RELAXED, __HIP_MEMORY_SCOPE_AGENT);
            }
            // lanes 0..7 poll S_h', lanes 8..15 poll Q_h' (own included)
            float v = 0.f;
            if (lane < 16) {
                const u64* addr = &zst[p * 16 + (lane & 8) + (lane & 7)];
                u64 x;
                do {
                    x = __hip_atomic_load(addr, __ATOMIC_RELAXED,
                                          __HIP_MEMORY_SCOPE_AGENT);
                } while ((unsigned)(x >> 32) != tag);
                union { unsigned u; float f; } cv; cv.u = (unsigned)x;
                v = cv.f;
            }
            // sum within each 8-group (all 64 lanes execute the shfls)
            v += __shfl_xor(v, 1);
            v += __shfl_xor(v, 2);
            v += __shfl_xor(v, 4);
            const float qt = __shfl(v, 8);                 // lane8 = sum Q
            if (lane == 0) {
                const float St  = v;
                const float mu  = St * (1.0f / E_);
                const float var = (qt - St * mu) * (1.0f / (E_ - 1));
                munv[0] = mu;
                munv[1] = 1.0f / (sqrtf(var) + EPS_);
            }
        } else if (wv >= 8) {
            // waves 8..15: poll all 512 values (element tid-512) into LDS.
            // Runs concurrently with wave0's stats exchange.
            const int i = tid - 512;
            const u64* addr = &zpb[p * E_ + i];
            u64 x;
            do {
                x = __hip_atomic_load(addr, __ATOMIC_RELAXED,
                                      __HIP_MEMORY_SCOPE_AGENT);
            } while ((unsigned)(x >> 32) != tag);
            union { unsigned u; float f; } cv; cv.u = (unsigned)x;
            zmbuf[i] = cv.f;
        }
        __syncthreads();                                   // B2

        if (tid < E_) {
            const float mu = munv[0], invd = munv[1];
            const float zl = gmm * (zmbuf[tid] - mu) * invd + btt;
            if (t == S_ - 1) {
                if (h == 0) zout[(size_t)b * E_ + tid] = zl;
            } else {
                zs[tid] = fmaf(e, sqrtE, zl);
            }
        }
        __syncthreads();                                   // B3
    }
}

// ---------------------------------------------------------------------------
// K2: y = z @ W_voc + b_voc. 250 blocks x 512 threads; each thread owns one
// vocab column for 8 batches (bg group). z reads are thread-uniform ->
// scalar-cache loads; W_voc streamed once (same cols across bg reuse L1).
// No atomics, bias folded, direct store.
// ---------------------------------------------------------------------------
__global__ __launch_bounds__(512) void logits_k(
    const float* __restrict__ zfin,  // (B,E)
    const float* __restrict__ Wvoc,  // (E,V)
    const float* __restrict__ bvoc,  // (V)
    float* __restrict__ y)           // (B,V)
{
    const int tid = threadIdx.x;
    const int col = blockIdx.x * 128 + (tid & 127);
    const int bg  = (tid >> 7) * 8;           // 0,8,16,24

    float acc[8] = {0.f, 0.f, 0.f, 0.f, 0.f, 0.f, 0.f, 0.f};
    const float* wp = Wvoc + col;
    const float* zp = zfin + (size_t)bg * E_;

    for (int k = 0; k < E_; k += 4) {
        const float w0 = wp[(size_t)(k + 0) * V_];
        const float w1 = wp[(size_t)(k + 1) * V_];
        const float w2 = wp[(size_t)(k + 2) * V_];
        const float w3 = wp[(size_t)(k + 3) * V_];
        #pragma unroll
        for (int g = 0; g < 8; ++g) {
            acc[g] = fmaf(zp[g * E_ + k + 0], w0, acc[g]);
            acc[g] = fmaf(zp[g * E_ + k + 1], w1, acc[g]);
            acc[g] = fmaf(zp[g * E_ + k + 2], w2, acc[g]);
            acc[g] = fmaf(zp[g * E_ + k + 3], w3, acc[g]);
        }
    }
    const float bv = bvoc[col];
    #pragma unroll
    for (int g = 0; g < 8; ++g)
        y[(size_t)(bg + g) * V_ + col] = acc[g] + bv;
}

// ---------------------------------------------------------------------------
// K3: per-batch log-sum-exp (bias already folded into y)
// ---------------------------------------------------------------------------
__global__ __launch_bounds__(1024) void lse_k(
    const float* __restrict__ y, float* __restrict__ corr)
{
    __shared__ float redm[16], redl[16];
    const int b = blockIdx.x;
    const int tid = threadIdx.x;
    const float* row = y + (size_t)b * V_;

    float m = -3.0e38f, l = 0.f;
    for (int v = tid; v < V_; v += 1024) {
        const float x = row[v];
        const float nm = fmaxf(m, x);
        l = l * __expf(m - nm) + __expf(x - nm);
        m = nm;
    }
    #pragma unroll
    for (int off = 32; off > 0; off >>= 1) {
        const float om = __shfl_down(m, off);
        const float ol = __shfl_down(l, off);
        const float nm = fmaxf(m, om);
        l = l * __expf(m - nm) + ol * __expf(om - nm);
        m = nm;
    }
    const int lane = tid & 63, wvv = tid >> 6;
    if (lane == 0) { redm[wvv] = m; redl[wvv] = l; }
    __syncthreads();
    if (tid == 0) {
        float M = redm[0], L = redl[0];
        for (int k = 1; k < 16; ++k) {
            const float nm = fmaxf(M, redm[k]);
            L = L * __expf(M - nm) + redl[k] * __expf(redm[k] - nm);
            M = nm;
        }
        corr[b] = M + logf(L);
    }
}

// ---------------------------------------------------------------------------
// K4: y -= corr[b]
// ---------------------------------------------------------------------------
__global__ __launch_bounds__(256) void fix_k(
    float* __restrict__ y, const float* __restrict__ corr)
{
    const int idx = blockIdx.x * 256 + threadIdx.x;   // float4 index
    const size_t o = (size_t)idx * 4;
    const int b = (int)(o / V_);
    const float cr = corr[b];
    v4 v = *(v4*)(y + o);
    v = v - cr;
    *(v4*)(y + o) = v;
}

// ---------------------------------------------------------------------------
extern "C" void kernel_launch(void* const* d_in, const int* in_sizes, int n_in,
                              void* d_out, int out_size, void* d_ws, size_t ws_size,
                              hipStream_t stream)
{
    (void)in_sizes; (void)n_in; (void)out_size; (void)ws_size;
    // 0=hidden_state (unused), 1=output_sequence, 2=emb_out, 3=W_dec,
    // 4=b_dec, 5=gamma, 6=beta, 7=W_voc, 8=b_voc
    const int*   seq  = (const int*)  d_in[1];
    const float* emb  = (const float*)d_in[2];
    const float* Wdec = (const float*)d_in[3];
    const float* bdec = (const float*)d_in[4];
    const float* gam  = (const float*)d_in[5];
    const float* bet  = (const float*)d_in[6];
    const float* Wvoc = (const float*)d_in[7];
    const float* bvoc = (const float*)d_in[8];

    float* out  = (float*)d_out;
    float* zout = out;            // B*E floats
    float* y    = out + B_ * E_;  // B*V floats

    // workspace layout: values (B*2*E u64) + stats (B*2*2*8 u64) + corr
    const size_t exch_u64 = (size_t)B_ * 2 * E_ + (size_t)B_ * 32;
    u64*   zpub = (u64*)d_ws;
    float* corr = (float*)((char*)d_ws + exch_u64 * sizeof(u64)); // B floats

    // tags must not alias t+1 from a previous replay — zero the exchange buf
    hipMemsetAsync(zpub, 0, exch_u64 * sizeof(u64), stream);

    hipLaunchKernelGGL(scan8w, dim3(B_ * NH_), dim3(1024), 0, stream,
                       seq, emb, Wdec, bdec, gam, bet, zout, zpub);
    hipLaunchKernelGGL(logits_k, dim3(V_ / 128), dim3(512), 0, stream,
                       zout, Wvoc, bvoc, y);
    hipLaunchKernelGGL(lse_k, dim3(B_), dim3(1024), 0, stream, y, corr);
    hipLaunchKernelGGL(fix_k, dim3(1000), dim3(256), 0, stream, y, corr);
}